// Round 1
// baseline (1947.394 us; speedup 1.0000x reference)
//
#include <hip/hip_runtime.h>
#include <hip/hip_bf16.h>

// GCN 2-layer forward for MI355X (gfx950), fp32.
// Pipeline:
//   1) deg = 1 + in-degree(dst)          (float atomics)
//   2) dinv = rsqrt(deg)
//   3) XW1 = x @ W1                      (W1 staged in LDS, wave-per-row)
//   4) agg1 += XW1[src]*dinv[s]*dinv[d]  (wave-per-edge, 64 lanes = 64 feats, atomics)
//   5) h1 = tanh(agg1 + XW1*dinv^2 + b1) (in place over agg1)
//   6) XW2 = h1 @ W2                     (thread-per-row)
//   7) agg2 += XW2[src]*norm             (thread-per-edge, 2 atomics)
//   8) h2 = tanh(agg2 + XW2*dinv^2 + b2); out = h2 @ Wc + bc

__global__ void k_init_deg(float* __restrict__ deg, int n) {
    int i = blockIdx.x * blockDim.x + threadIdx.x;
    if (i < n) deg[i] = 1.0f;
}

__global__ void k_deg_atomic(const int* __restrict__ dst, float* __restrict__ deg, int E) {
    int i = blockIdx.x * blockDim.x + threadIdx.x;
    int stride = gridDim.x * blockDim.x;
    for (; i < E; i += stride) atomicAdd(&deg[dst[i]], 1.0f);
}

__global__ void k_rsqrt(float* __restrict__ deg, int n) {
    int i = blockIdx.x * blockDim.x + threadIdx.x;
    if (i < n) deg[i] = rsqrtf(deg[i]);
}

// XW1 = x[n,128] @ W1[128,64]. One wave per row; lane j computes column j.
__global__ void k_gemm1(const float* __restrict__ x, const float* __restrict__ W1,
                        float* __restrict__ xw, int n) {
    __shared__ float Ws[128 * 64];
    for (int i = threadIdx.x; i < 128 * 64; i += blockDim.x) Ws[i] = W1[i];
    __syncthreads();
    int wave = threadIdx.x >> 6;
    int lane = threadIdx.x & 63;
    int wavesTotal = gridDim.x * (blockDim.x >> 6);
    for (int row = blockIdx.x * (blockDim.x >> 6) + wave; row < n; row += wavesTotal) {
        const float* xr = x + (size_t)row * 128;
        float acc = 0.0f;
        #pragma unroll
        for (int k = 0; k < 128; k += 4) {
            float4 xv = *reinterpret_cast<const float4*>(xr + k);
            acc = fmaf(xv.x, Ws[(k + 0) * 64 + lane], acc);
            acc = fmaf(xv.y, Ws[(k + 1) * 64 + lane], acc);
            acc = fmaf(xv.z, Ws[(k + 2) * 64 + lane], acc);
            acc = fmaf(xv.w, Ws[(k + 3) * 64 + lane], acc);
        }
        xw[(size_t)row * 64 + lane] = acc;
    }
}

// agg1[dst] += XW1[src] * dinv[src]*dinv[dst]; one wave per edge (lane=feature).
__global__ void k_scatter1(const int* __restrict__ src, const int* __restrict__ dst,
                           const float* __restrict__ dinv, const float* __restrict__ xw,
                           float* __restrict__ agg, long long total) {
    long long idx = (long long)blockIdx.x * blockDim.x + threadIdx.x;
    long long stride = (long long)gridDim.x * blockDim.x;
    for (; idx < total; idx += stride) {
        int e = (int)(idx >> 6);
        int f = (int)(idx & 63);
        int s = src[e];
        int d = dst[e];
        float norm = dinv[s] * dinv[d];
        float v = xw[(size_t)s * 64 + f] * norm;
        atomicAdd(&agg[(size_t)d * 64 + f], v);
    }
}

// h1 = tanh(agg1 + XW1*dinv^2 + b1), written in place over agg1.
__global__ void k_post1(float* __restrict__ agg, const float* __restrict__ xw,
                        const float* __restrict__ dinv, const float* __restrict__ b1,
                        int total) {
    int idx = blockIdx.x * blockDim.x + threadIdx.x;
    int stride = gridDim.x * blockDim.x;
    for (; idx < total; idx += stride) {
        int i = idx >> 6;
        int f = idx & 63;
        float di = dinv[i];
        agg[idx] = tanhf(agg[idx] + xw[idx] * (di * di) + b1[f]);
    }
}

// XW2 = h1[n,64] @ W2[64,2]; thread per row.
__global__ void k_gemm2(const float* __restrict__ h1, const float* __restrict__ W2,
                        float* __restrict__ xw2, int n) {
    __shared__ float Ws[128];
    if (threadIdx.x < 128) Ws[threadIdx.x] = W2[threadIdx.x];
    __syncthreads();
    int r = blockIdx.x * blockDim.x + threadIdx.x;
    int stride = gridDim.x * blockDim.x;
    for (; r < n; r += stride) {
        const float* hr = h1 + (size_t)r * 64;
        float a0 = 0.0f, a1 = 0.0f;
        #pragma unroll
        for (int k = 0; k < 64; k += 4) {
            float4 hv = *reinterpret_cast<const float4*>(hr + k);
            a0 = fmaf(hv.x, Ws[(k + 0) * 2 + 0], a0);
            a1 = fmaf(hv.x, Ws[(k + 0) * 2 + 1], a1);
            a0 = fmaf(hv.y, Ws[(k + 1) * 2 + 0], a0);
            a1 = fmaf(hv.y, Ws[(k + 1) * 2 + 1], a1);
            a0 = fmaf(hv.z, Ws[(k + 2) * 2 + 0], a0);
            a1 = fmaf(hv.z, Ws[(k + 2) * 2 + 1], a1);
            a0 = fmaf(hv.w, Ws[(k + 3) * 2 + 0], a0);
            a1 = fmaf(hv.w, Ws[(k + 3) * 2 + 1], a1);
        }
        float2 o = make_float2(a0, a1);
        *reinterpret_cast<float2*>(xw2 + (size_t)r * 2) = o;
    }
}

// agg2[dst] += XW2[src]*norm; thread per edge, 2 atomics.
__global__ void k_scatter2(const int* __restrict__ src, const int* __restrict__ dst,
                           const float* __restrict__ dinv, const float* __restrict__ xw2,
                           float* __restrict__ agg2, int E) {
    int e = blockIdx.x * blockDim.x + threadIdx.x;
    int stride = gridDim.x * blockDim.x;
    for (; e < E; e += stride) {
        int s = src[e];
        int d = dst[e];
        float norm = dinv[s] * dinv[d];
        float2 v = *reinterpret_cast<const float2*>(xw2 + (size_t)s * 2);
        atomicAdd(&agg2[(size_t)d * 2 + 0], v.x * norm);
        atomicAdd(&agg2[(size_t)d * 2 + 1], v.y * norm);
    }
}

// h2 = tanh(agg2 + XW2*dinv^2 + b2); out = h2 @ Wc + bc. Writes both outputs.
__global__ void k_post2(const float* __restrict__ agg2, const float* __restrict__ xw2,
                        const float* __restrict__ dinv, const float* __restrict__ b2,
                        const float* __restrict__ Wc, const float* __restrict__ bc,
                        float* __restrict__ out, float* __restrict__ hout, int n) {
    int i = blockIdx.x * blockDim.x + threadIdx.x;
    int stride = gridDim.x * blockDim.x;
    for (; i < n; i += stride) {
        float di = dinv[i];
        float d2 = di * di;
        float2 a = *reinterpret_cast<const float2*>(agg2 + (size_t)i * 2);
        float2 v = *reinterpret_cast<const float2*>(xw2 + (size_t)i * 2);
        float h0 = tanhf(a.x + v.x * d2 + b2[0]);
        float h1 = tanhf(a.y + v.y * d2 + b2[1]);
        *reinterpret_cast<float2*>(hout + (size_t)i * 2) = make_float2(h0, h1);
        float4 o;
        o.x = fmaf(h0, Wc[0], fmaf(h1, Wc[4], bc[0]));
        o.y = fmaf(h0, Wc[1], fmaf(h1, Wc[5], bc[1]));
        o.z = fmaf(h0, Wc[2], fmaf(h1, Wc[6], bc[2]));
        o.w = fmaf(h0, Wc[3], fmaf(h1, Wc[7], bc[3]));
        *reinterpret_cast<float4*>(out + (size_t)i * 4) = o;
    }
}

extern "C" void kernel_launch(void* const* d_in, const int* in_sizes, int n_in,
                              void* d_out, int out_size, void* d_ws, size_t ws_size,
                              hipStream_t stream) {
    const float* x  = (const float*)d_in[0];
    const int* ei   = (const int*)d_in[1];
    const float* W1 = (const float*)d_in[2];
    const float* b1 = (const float*)d_in[3];
    const float* W2 = (const float*)d_in[4];
    const float* b2 = (const float*)d_in[5];
    const float* Wc = (const float*)d_in[6];
    const float* bc = (const float*)d_in[7];

    const int N = in_sizes[0] / 128;
    const int E = in_sizes[1] / 2;
    const int* src = ei;
    const int* dst = ei + E;

    float* out  = (float*)d_out;          // [N,4]
    float* hout = out + (size_t)N * 4;    // [N,2]

    float* ws   = (float*)d_ws;
    float* dinv = ws;                     // N
    float* xw1  = dinv + N;               // N*64
    float* agg1 = xw1 + (size_t)N * 64;   // N*64 (becomes h1)
    float* xw2  = agg1 + (size_t)N * 64;  // N*2
    float* agg2 = xw2 + (size_t)N * 2;    // N*2

    // Zero accumulators (async memset is graph-capture legal).
    hipMemsetAsync(agg1, 0, (size_t)N * 64 * sizeof(float), stream);
    hipMemsetAsync(agg2, 0, (size_t)N * 2 * sizeof(float), stream);

    // Degrees -> dinv.
    k_init_deg<<<(N + 255) / 256, 256, 0, stream>>>(dinv, N);
    k_deg_atomic<<<2048, 256, 0, stream>>>(dst, dinv, E);
    k_rsqrt<<<(N + 255) / 256, 256, 0, stream>>>(dinv, N);

    // Layer 1.
    k_gemm1<<<2048, 256, 0, stream>>>(x, W1, xw1, N);
    long long total1 = (long long)E * 64;
    k_scatter1<<<8192, 256, 0, stream>>>(src, dst, dinv, xw1, agg1, total1);
    k_post1<<<4096, 256, 0, stream>>>(agg1, xw1, dinv, b1, N * 64);

    // Layer 2.
    k_gemm2<<<2048, 256, 0, stream>>>(agg1, W2, xw2, N);
    k_scatter2<<<2048, 256, 0, stream>>>(src, dst, dinv, xw2, agg2, E);

    // Epilogue + classifier.
    k_post2<<<(N + 255) / 256, 256, 0, stream>>>(agg2, xw2, dinv, b2, Wc, bc, out, hout, N);
}

// Round 2
// 1511.803 us; speedup vs baseline: 1.2881x; 1.2881x over previous
//
#include <hip/hip_runtime.h>
#include <hip/hip_bf16.h>

// GCN 2-layer forward, CSR-gather formulation (no float atomics).
// Pipeline per call:
//   memset cnt; hist(dst)->cnt; dinv=rsqrt(1+cnt); scan(cnt)->rowptr;
//   memset cnt (reuse as cursor); fill csr_src;
//   gemm1: xw1 = x@W1 (x staged in LDS, W1 in VGPRs);
//   agg1 (fused): h1=tanh(sum_csr + self + b1); xw2 = h1@W2 via wave reduce;
//   agg2 (fused): h2=tanh(sum_csr + self + b2); out = h2@Wc+bc. Writes both outputs.

__global__ void k_hist(const int* __restrict__ dst, int* __restrict__ cnt, int E) {
    int i = blockIdx.x * blockDim.x + threadIdx.x;
    int st = gridDim.x * blockDim.x;
    for (; i < E; i += st) atomicAdd(&cnt[dst[i]], 1);
}

__global__ void k_dinv(const int* __restrict__ cnt, float* __restrict__ dinv, int n) {
    int i = blockIdx.x * blockDim.x + threadIdx.x;
    if (i < n) dinv[i] = rsqrtf(1.0f + (float)cnt[i]);
}

// Per-block (1024 elems) sum of cnt -> bsum[b]
__global__ void k_scan_bsum(const int* __restrict__ cnt, int* __restrict__ bsum, int n) {
    __shared__ int lds[256];
    int base = blockIdx.x * 1024;
    int s = 0;
    for (int i = threadIdx.x; i < 1024; i += 256) {
        int g = base + i;
        if (g < n) s += cnt[g];
    }
    lds[threadIdx.x] = s;
    __syncthreads();
    for (int off = 128; off > 0; off >>= 1) {
        if (threadIdx.x < off) lds[threadIdx.x] += lds[threadIdx.x + off];
        __syncthreads();
    }
    if (threadIdx.x == 0) bsum[blockIdx.x] = lds[0];
}

// Exclusive scan of bsum (nb ~ 98, single thread is fine); also rowptr[n]=total.
__global__ void k_scan_off(int* __restrict__ bsum, int* __restrict__ rowptr, int nb, int n) {
    if (blockIdx.x == 0 && threadIdx.x == 0) {
        int run = 0;
        for (int i = 0; i < nb; i++) { int t = bsum[i]; bsum[i] = run; run += t; }
        rowptr[n] = run;
    }
}

// Final: exclusive scan within block + block offset -> rowptr[i]
__global__ void k_scan_final(const int* __restrict__ cnt, const int* __restrict__ bsum,
                             int* __restrict__ rowptr, int n) {
    __shared__ int lds[256];
    int base = blockIdx.x * 1024;
    int idx0 = base + threadIdx.x * 4;
    int v[4];
    #pragma unroll
    for (int i = 0; i < 4; i++) { int g = idx0 + i; v[i] = (g < n) ? cnt[g] : 0; }
    int t = v[0] + v[1] + v[2] + v[3];
    lds[threadIdx.x] = t;
    __syncthreads();
    for (int off = 1; off < 256; off <<= 1) {
        int val = lds[threadIdx.x];
        int add = (threadIdx.x >= off) ? lds[threadIdx.x - off] : 0;
        __syncthreads();
        lds[threadIdx.x] = val + add;
        __syncthreads();
    }
    int run = (threadIdx.x ? lds[threadIdx.x - 1] : 0) + bsum[blockIdx.x];
    #pragma unroll
    for (int i = 0; i < 4; i++) {
        int g = idx0 + i;
        if (g < n) rowptr[g] = run;
        run += v[i];
    }
}

__global__ void k_fill(const int* __restrict__ src, const int* __restrict__ dst,
                       const int* __restrict__ rowptr, int* __restrict__ cursor,
                       int* __restrict__ csr_src, int E) {
    int e = blockIdx.x * blockDim.x + threadIdx.x;
    int st = gridDim.x * blockDim.x;
    for (; e < E; e += st) {
        int d = dst[e];
        int p = rowptr[d] + atomicAdd(&cursor[d], 1);
        csr_src[p] = src[e];
    }
}

// xw1 = x[n,128] @ W1[128,64]. W1 column held in 128 VGPRs per lane;
// x rows staged via coalesced float4 into LDS, read back as broadcast b128.
__global__ void k_gemm1(const float* __restrict__ x, const float* __restrict__ W1,
                        float* __restrict__ xw, int n) {
    __shared__ float xs[8][128];
    int lane = threadIdx.x & 63;
    int wav = threadIdx.x >> 6;  // 0..3
    float w[128];
    #pragma unroll
    for (int k = 0; k < 128; k++) w[k] = W1[k * 64 + lane];
    int nbatch = (n + 7) >> 3;
    for (int b = blockIdx.x; b < nbatch; b += gridDim.x) {
        int rb = b * 8;
        {
            int r = threadIdx.x >> 5;         // 0..7
            int c = (threadIdx.x & 31) * 4;   // 0..124
            int row = rb + r;
            float4 v = make_float4(0.f, 0.f, 0.f, 0.f);
            if (row < n) v = *reinterpret_cast<const float4*>(x + (size_t)row * 128 + c);
            *reinterpret_cast<float4*>(&xs[r][c]) = v;
        }
        __syncthreads();
        int r0 = rb + wav * 2, r1 = r0 + 1;
        float acc0 = 0.f, acc1 = 0.f;
        #pragma unroll
        for (int k4 = 0; k4 < 32; k4++) {
            float4 a = *reinterpret_cast<const float4*>(&xs[wav * 2][k4 * 4]);
            float4 c2 = *reinterpret_cast<const float4*>(&xs[wav * 2 + 1][k4 * 4]);
            acc0 = fmaf(a.x, w[4 * k4 + 0], acc0);
            acc0 = fmaf(a.y, w[4 * k4 + 1], acc0);
            acc0 = fmaf(a.z, w[4 * k4 + 2], acc0);
            acc0 = fmaf(a.w, w[4 * k4 + 3], acc0);
            acc1 = fmaf(c2.x, w[4 * k4 + 0], acc1);
            acc1 = fmaf(c2.y, w[4 * k4 + 1], acc1);
            acc1 = fmaf(c2.z, w[4 * k4 + 2], acc1);
            acc1 = fmaf(c2.w, w[4 * k4 + 3], acc1);
        }
        if (r0 < n) xw[(size_t)r0 * 64 + lane] = acc0;
        if (r1 < n) xw[(size_t)r1 * 64 + lane] = acc1;
        __syncthreads();
    }
}

// Fused layer1 aggregate + tanh + GEMM2 (64->2 via wave reduction).
// One wave per dst node; lane = feature.
__global__ void k_agg1(const int* __restrict__ rowptr, const int* __restrict__ csr_src,
                       const float* __restrict__ dinv, const float* __restrict__ xw1,
                       const float* __restrict__ b1, const float* __restrict__ W2,
                       float* __restrict__ xw2, int n) {
    int lane = threadIdx.x & 63;
    float b1v = b1[lane];
    float w2a = W2[lane * 2 + 0];
    float w2b = W2[lane * 2 + 1];
    int wid = blockIdx.x * (blockDim.x >> 6) + (threadIdx.x >> 6);
    int wtot = gridDim.x * (blockDim.x >> 6);
    for (int d = wid; d < n; d += wtot) {
        int base = rowptr[d], end = rowptr[d + 1];
        float dd = dinv[d];
        float acc = xw1[(size_t)d * 64 + lane] * dd * dd;  // self loop
        int j = base;
        for (; j + 4 <= end; j += 4) {
            int s0 = csr_src[j + 0], s1 = csr_src[j + 1];
            int s2 = csr_src[j + 2], s3 = csr_src[j + 3];
            float n0 = dinv[s0] * dd, n1 = dinv[s1] * dd;
            float n2 = dinv[s2] * dd, n3 = dinv[s3] * dd;
            float v0 = xw1[(size_t)s0 * 64 + lane];
            float v1 = xw1[(size_t)s1 * 64 + lane];
            float v2 = xw1[(size_t)s2 * 64 + lane];
            float v3 = xw1[(size_t)s3 * 64 + lane];
            acc = fmaf(v0, n0, acc);
            acc = fmaf(v1, n1, acc);
            acc = fmaf(v2, n2, acc);
            acc = fmaf(v3, n3, acc);
        }
        for (; j < end; ++j) {
            int s = csr_src[j];
            acc = fmaf(xw1[(size_t)s * 64 + lane], dinv[s] * dd, acc);
        }
        float h = tanhf(acc + b1v);
        float p0 = h * w2a, p1 = h * w2b;
        #pragma unroll
        for (int m = 32; m >= 1; m >>= 1) {
            p0 += __shfl_xor(p0, m);
            p1 += __shfl_xor(p1, m);
        }
        if (lane == 0) *reinterpret_cast<float2*>(xw2 + (size_t)d * 2) = make_float2(p0, p1);
    }
}

// Fused layer2 aggregate + tanh + classifier. One wave per node:
// 32 edge-slots x 2 features in parallel, shfl tree reduce over slots.
__global__ void k_agg2(const int* __restrict__ rowptr, const int* __restrict__ csr_src,
                       const float* __restrict__ dinv, const float* __restrict__ xw2,
                       const float* __restrict__ b2, const float* __restrict__ Wc,
                       const float* __restrict__ bc,
                       float* __restrict__ out, float* __restrict__ hout, int n) {
    int lane = threadIdx.x & 63;
    int slot = lane >> 1;  // 0..31
    int f = lane & 1;      // feature 0/1
    float b2v = b2[f];
    int wid = blockIdx.x * (blockDim.x >> 6) + (threadIdx.x >> 6);
    int wtot = gridDim.x * (blockDim.x >> 6);
    for (int d = wid; d < n; d += wtot) {
        int base = rowptr[d], end = rowptr[d + 1];
        float dd = dinv[d];
        float acc = (slot == 0) ? xw2[(size_t)d * 2 + f] * dd * dd : 0.f;  // self loop once
        for (int j = base + slot; j < end; j += 32) {
            int s = csr_src[j];
            acc = fmaf(xw2[(size_t)s * 2 + f], dinv[s] * dd, acc);
        }
        #pragma unroll
        for (int m = 32; m >= 2; m >>= 1) acc += __shfl_xor(acc, m);
        float h = tanhf(acc + b2v);          // lane0: h(f=0), lane1: h(f=1), replicated
        float other = __shfl_xor(h, 1);
        if (lane == 0) {
            *reinterpret_cast<float2*>(hout + (size_t)d * 2) = make_float2(h, other);
            float4 o;
            o.x = fmaf(h, Wc[0], fmaf(other, Wc[4], bc[0]));
            o.y = fmaf(h, Wc[1], fmaf(other, Wc[5], bc[1]));
            o.z = fmaf(h, Wc[2], fmaf(other, Wc[6], bc[2]));
            o.w = fmaf(h, Wc[3], fmaf(other, Wc[7], bc[3]));
            *reinterpret_cast<float4*>(out + (size_t)d * 4) = o;
        }
    }
}

extern "C" void kernel_launch(void* const* d_in, const int* in_sizes, int n_in,
                              void* d_out, int out_size, void* d_ws, size_t ws_size,
                              hipStream_t stream) {
    const float* x  = (const float*)d_in[0];
    const int* ei   = (const int*)d_in[1];
    const float* W1 = (const float*)d_in[2];
    const float* b1 = (const float*)d_in[3];
    const float* W2 = (const float*)d_in[4];
    const float* b2 = (const float*)d_in[5];
    const float* Wc = (const float*)d_in[6];
    const float* bc = (const float*)d_in[7];

    const int N = in_sizes[0] / 128;
    const int E = in_sizes[1] / 2;
    const int* src = ei;
    const int* dst = ei + E;

    float* out  = (float*)d_out;        // [N,4]
    float* hout = out + (size_t)N * 4;  // [N,2]

    // Workspace layout (keep 16B alignment: big 16-divisible arrays first).
    char* ws = (char*)d_ws;
    int*   csr_src = (int*)ws;                           // E
    float* xw1     = (float*)(csr_src + E);              // 64N
    int*   cnt     = (int*)(xw1 + (size_t)N * 64);       // N (hist, then cursor)
    float* dinv    = (float*)(cnt + N);                  // N
    float* xw2     = dinv + N;                           // 2N
    int*   rowptr  = (int*)(xw2 + (size_t)N * 2);        // N+1
    int*   bsum    = rowptr + N + 1;                     // ~128

    const int NB = (N + 1023) / 1024;

    hipMemsetAsync(cnt, 0, (size_t)N * sizeof(int), stream);
    k_hist<<<1024, 256, 0, stream>>>(dst, cnt, E);
    k_dinv<<<(N + 255) / 256, 256, 0, stream>>>(cnt, dinv, N);
    k_scan_bsum<<<NB, 256, 0, stream>>>(cnt, bsum, N);
    k_scan_off<<<1, 64, 0, stream>>>(bsum, rowptr, NB, N);
    k_scan_final<<<NB, 256, 0, stream>>>(cnt, bsum, rowptr, N);
    hipMemsetAsync(cnt, 0, (size_t)N * sizeof(int), stream);  // reuse as cursor
    k_fill<<<1024, 256, 0, stream>>>(src, dst, rowptr, cnt, csr_src, E);

    k_gemm1<<<1024, 256, 0, stream>>>(x, W1, xw1, N);
    k_agg1<<<2048, 256, 0, stream>>>(rowptr, csr_src, dinv, xw1, b1, W2, xw2, N);
    k_agg2<<<2048, 256, 0, stream>>>(rowptr, csr_src, dinv, xw2, b2, Wc, bc, out, hout, N);
}

// Round 3
// 586.084 us; speedup vs baseline: 3.3227x; 2.5795x over previous
//
#include <hip/hip_runtime.h>
#include <hip/hip_bf16.h>

// GCN 2-layer forward, CSR-gather formulation (no float atomics).
// R3 change: gemm1 rewritten thread-per-row with static acc[64] in VGPRs and
// uniform (scalar) W1 loads — removes the scratch spill that cost 1.6 GB of
// local-memory traffic in R2 (VGPR_Count=64 with a float w[128] array).

__global__ void k_hist(const int* __restrict__ dst, int* __restrict__ cnt, int E) {
    int i = blockIdx.x * blockDim.x + threadIdx.x;
    int st = gridDim.x * blockDim.x;
    for (; i < E; i += st) atomicAdd(&cnt[dst[i]], 1);
}

__global__ void k_dinv(const int* __restrict__ cnt, float* __restrict__ dinv, int n) {
    int i = blockIdx.x * blockDim.x + threadIdx.x;
    if (i < n) dinv[i] = rsqrtf(1.0f + (float)cnt[i]);
}

// Per-block (1024 elems) sum of cnt -> bsum[b]
__global__ void k_scan_bsum(const int* __restrict__ cnt, int* __restrict__ bsum, int n) {
    __shared__ int lds[256];
    int base = blockIdx.x * 1024;
    int s = 0;
    for (int i = threadIdx.x; i < 1024; i += 256) {
        int g = base + i;
        if (g < n) s += cnt[g];
    }
    lds[threadIdx.x] = s;
    __syncthreads();
    for (int off = 128; off > 0; off >>= 1) {
        if (threadIdx.x < off) lds[threadIdx.x] += lds[threadIdx.x + off];
        __syncthreads();
    }
    if (threadIdx.x == 0) bsum[blockIdx.x] = lds[0];
}

// Exclusive scan of bsum (nb ~ 98, single thread is fine); also rowptr[n]=total.
__global__ void k_scan_off(int* __restrict__ bsum, int* __restrict__ rowptr, int nb, int n) {
    if (blockIdx.x == 0 && threadIdx.x == 0) {
        int run = 0;
        for (int i = 0; i < nb; i++) { int t = bsum[i]; bsum[i] = run; run += t; }
        rowptr[n] = run;
    }
}

// Final: exclusive scan within block + block offset -> rowptr[i]
__global__ void k_scan_final(const int* __restrict__ cnt, const int* __restrict__ bsum,
                             int* __restrict__ rowptr, int n) {
    __shared__ int lds[256];
    int base = blockIdx.x * 1024;
    int idx0 = base + threadIdx.x * 4;
    int v[4];
    #pragma unroll
    for (int i = 0; i < 4; i++) { int g = idx0 + i; v[i] = (g < n) ? cnt[g] : 0; }
    int t = v[0] + v[1] + v[2] + v[3];
    lds[threadIdx.x] = t;
    __syncthreads();
    for (int off = 1; off < 256; off <<= 1) {
        int val = lds[threadIdx.x];
        int add = (threadIdx.x >= off) ? lds[threadIdx.x - off] : 0;
        __syncthreads();
        lds[threadIdx.x] = val + add;
        __syncthreads();
    }
    int run = (threadIdx.x ? lds[threadIdx.x - 1] : 0) + bsum[blockIdx.x];
    #pragma unroll
    for (int i = 0; i < 4; i++) {
        int g = idx0 + i;
        if (g < n) rowptr[g] = run;
        run += v[i];
    }
}

__global__ void k_fill(const int* __restrict__ src, const int* __restrict__ dst,
                       const int* __restrict__ rowptr, int* __restrict__ cursor,
                       int* __restrict__ csr_src, int E) {
    int e = blockIdx.x * blockDim.x + threadIdx.x;
    int st = gridDim.x * blockDim.x;
    for (; e < E; e += st) {
        int d = dst[e];
        int p = rowptr[d] + atomicAdd(&cursor[d], 1);
        csr_src[p] = src[e];
    }
}

// xw1 = x[n,128] @ W1[128,64]. Thread-per-row; acc[64] in VGPRs (all indices
// compile-time via full unroll); W1 addresses are lane-uniform -> scalar loads.
__global__ __launch_bounds__(256) void k_gemm1(const float* __restrict__ x,
                                               const float* __restrict__ W1,
                                               float* __restrict__ xw, int n) {
    int row = blockIdx.x * blockDim.x + threadIdx.x;
    if (row >= n) return;
    const float* xr = x + (size_t)row * 128;

    float acc[64];
    #pragma unroll
    for (int c = 0; c < 64; ++c) acc[c] = 0.f;

    for (int k4 = 0; k4 < 32; ++k4) {  // dynamic loop: small body, x read once
        float4 xv = *reinterpret_cast<const float4*>(xr + k4 * 4);
        const float* wp = W1 + (size_t)k4 * 4 * 64;  // rows k4*4 .. k4*4+3
        #pragma unroll
        for (int c = 0; c < 64; ++c) {
            acc[c] = fmaf(xv.x, wp[c], acc[c]);
            acc[c] = fmaf(xv.y, wp[64 + c], acc[c]);
            acc[c] = fmaf(xv.z, wp[128 + c], acc[c]);
            acc[c] = fmaf(xv.w, wp[192 + c], acc[c]);
        }
    }

    float* outp = xw + (size_t)row * 64;
    #pragma unroll
    for (int c = 0; c < 64; c += 4) {
        *reinterpret_cast<float4*>(outp + c) =
            make_float4(acc[c], acc[c + 1], acc[c + 2], acc[c + 3]);
    }
}

// Fused layer1 aggregate + tanh + GEMM2 (64->2 via wave reduction).
// One wave per dst node; lane = feature.
__global__ void k_agg1(const int* __restrict__ rowptr, const int* __restrict__ csr_src,
                       const float* __restrict__ dinv, const float* __restrict__ xw1,
                       const float* __restrict__ b1, const float* __restrict__ W2,
                       float* __restrict__ xw2, int n) {
    int lane = threadIdx.x & 63;
    float b1v = b1[lane];
    float w2a = W2[lane * 2 + 0];
    float w2b = W2[lane * 2 + 1];
    int wid = blockIdx.x * (blockDim.x >> 6) + (threadIdx.x >> 6);
    int wtot = gridDim.x * (blockDim.x >> 6);
    for (int d = wid; d < n; d += wtot) {
        int base = rowptr[d], end = rowptr[d + 1];
        float dd = dinv[d];
        float acc = xw1[(size_t)d * 64 + lane] * dd * dd;  // self loop
        int j = base;
        for (; j + 4 <= end; j += 4) {
            int s0 = csr_src[j + 0], s1 = csr_src[j + 1];
            int s2 = csr_src[j + 2], s3 = csr_src[j + 3];
            float n0 = dinv[s0] * dd, n1 = dinv[s1] * dd;
            float n2 = dinv[s2] * dd, n3 = dinv[s3] * dd;
            float v0 = xw1[(size_t)s0 * 64 + lane];
            float v1 = xw1[(size_t)s1 * 64 + lane];
            float v2 = xw1[(size_t)s2 * 64 + lane];
            float v3 = xw1[(size_t)s3 * 64 + lane];
            acc = fmaf(v0, n0, acc);
            acc = fmaf(v1, n1, acc);
            acc = fmaf(v2, n2, acc);
            acc = fmaf(v3, n3, acc);
        }
        for (; j < end; ++j) {
            int s = csr_src[j];
            acc = fmaf(xw1[(size_t)s * 64 + lane], dinv[s] * dd, acc);
        }
        float h = tanhf(acc + b1v);
        float p0 = h * w2a, p1 = h * w2b;
        #pragma unroll
        for (int m = 32; m >= 1; m >>= 1) {
            p0 += __shfl_xor(p0, m);
            p1 += __shfl_xor(p1, m);
        }
        if (lane == 0) *reinterpret_cast<float2*>(xw2 + (size_t)d * 2) = make_float2(p0, p1);
    }
}

// Fused layer2 aggregate + tanh + classifier. One wave per node:
// 32 edge-slots x 2 features in parallel, shfl tree reduce over slots.
__global__ void k_agg2(const int* __restrict__ rowptr, const int* __restrict__ csr_src,
                       const float* __restrict__ dinv, const float* __restrict__ xw2,
                       const float* __restrict__ b2, const float* __restrict__ Wc,
                       const float* __restrict__ bc,
                       float* __restrict__ out, float* __restrict__ hout, int n) {
    int lane = threadIdx.x & 63;
    int slot = lane >> 1;  // 0..31
    int f = lane & 1;      // feature 0/1
    float b2v = b2[f];
    int wid = blockIdx.x * (blockDim.x >> 6) + (threadIdx.x >> 6);
    int wtot = gridDim.x * (blockDim.x >> 6);
    for (int d = wid; d < n; d += wtot) {
        int base = rowptr[d], end = rowptr[d + 1];
        float dd = dinv[d];
        float acc = (slot == 0) ? xw2[(size_t)d * 2 + f] * dd * dd : 0.f;  // self loop once
        for (int j = base + slot; j < end; j += 32) {
            int s = csr_src[j];
            acc = fmaf(xw2[(size_t)s * 2 + f], dinv[s] * dd, acc);
        }
        #pragma unroll
        for (int m = 32; m >= 2; m >>= 1) acc += __shfl_xor(acc, m);
        float h = tanhf(acc + b2v);          // lane0: h(f=0), lane1: h(f=1), replicated
        float other = __shfl_xor(h, 1);
        if (lane == 0) {
            *reinterpret_cast<float2*>(hout + (size_t)d * 2) = make_float2(h, other);
            float4 o;
            o.x = fmaf(h, Wc[0], fmaf(other, Wc[4], bc[0]));
            o.y = fmaf(h, Wc[1], fmaf(other, Wc[5], bc[1]));
            o.z = fmaf(h, Wc[2], fmaf(other, Wc[6], bc[2]));
            o.w = fmaf(h, Wc[3], fmaf(other, Wc[7], bc[3]));
            *reinterpret_cast<float4*>(out + (size_t)d * 4) = o;
        }
    }
}

extern "C" void kernel_launch(void* const* d_in, const int* in_sizes, int n_in,
                              void* d_out, int out_size, void* d_ws, size_t ws_size,
                              hipStream_t stream) {
    const float* x  = (const float*)d_in[0];
    const int* ei   = (const int*)d_in[1];
    const float* W1 = (const float*)d_in[2];
    const float* b1 = (const float*)d_in[3];
    const float* W2 = (const float*)d_in[4];
    const float* b2 = (const float*)d_in[5];
    const float* Wc = (const float*)d_in[6];
    const float* bc = (const float*)d_in[7];

    const int N = in_sizes[0] / 128;
    const int E = in_sizes[1] / 2;
    const int* src = ei;
    const int* dst = ei + E;

    float* out  = (float*)d_out;        // [N,4]
    float* hout = out + (size_t)N * 4;  // [N,2]

    // Workspace layout (keep 16B alignment: big 16-divisible arrays first).
    char* ws = (char*)d_ws;
    int*   csr_src = (int*)ws;                           // E
    float* xw1     = (float*)(csr_src + E);              // 64N
    int*   cnt     = (int*)(xw1 + (size_t)N * 64);       // N (hist, then cursor)
    float* dinv    = (float*)(cnt + N);                  // N
    float* xw2     = dinv + N;                           // 2N
    int*   rowptr  = (int*)(xw2 + (size_t)N * 2);        // N+1
    int*   bsum    = rowptr + N + 1;                     // ~128

    const int NB = (N + 1023) / 1024;

    hipMemsetAsync(cnt, 0, (size_t)N * sizeof(int), stream);
    k_hist<<<1024, 256, 0, stream>>>(dst, cnt, E);
    k_dinv<<<(N + 255) / 256, 256, 0, stream>>>(cnt, dinv, N);
    k_scan_bsum<<<NB, 256, 0, stream>>>(cnt, bsum, N);
    k_scan_off<<<1, 64, 0, stream>>>(bsum, rowptr, NB, N);
    k_scan_final<<<NB, 256, 0, stream>>>(cnt, bsum, rowptr, N);
    hipMemsetAsync(cnt, 0, (size_t)N * sizeof(int), stream);  // reuse as cursor
    k_fill<<<1024, 256, 0, stream>>>(src, dst, rowptr, cnt, csr_src, E);

    k_gemm1<<<(N + 255) / 256, 256, 0, stream>>>(x, W1, xw1, N);
    k_agg1<<<2048, 256, 0, stream>>>(rowptr, csr_src, dinv, xw1, b1, W2, xw2, N);
    k_agg2<<<2048, 256, 0, stream>>>(rowptr, csr_src, dinv, xw2, b2, Wc, bc, out, hout, N);
}

// Round 4
// 505.781 us; speedup vs baseline: 3.8503x; 1.1588x over previous
//
#include <hip/hip_runtime.h>
#include <hip/hip_bf16.h>

// GCN 2-layer forward, CSR-gather formulation (no float atomics).
// R4 change: k_hist/k_fill bucketed by dst into 8 node-range buckets with
// team = blockIdx.x % 8 (XCD round-robin heuristic). Each team scans ALL edges
// but only handles its bucket -> scatter writes + cursor atomics stay in one
// XCD's L2, lines merge before eviction (R3: 197 MB partial-line evictions for
// a 12.8 MB array). Correct regardless of the actual block->XCD mapping.

#define NTEAM 8

__global__ void k_hist8(const int* __restrict__ dst, int* __restrict__ cnt,
                        int E, int n) {
    int team = blockIdx.x & (NTEAM - 1);
    int sub  = blockIdx.x >> 3;
    int nsub = gridDim.x >> 3;
    int nb   = (n + NTEAM - 1) / NTEAM;
    int lo = team * nb;
    int hi = min(n, lo + nb);
    for (int e = sub * blockDim.x + threadIdx.x; e < E; e += nsub * blockDim.x) {
        int d = dst[e];
        if (d >= lo && d < hi) atomicAdd(&cnt[d], 1);
    }
}

__global__ void k_fill8(const int* __restrict__ src, const int* __restrict__ dst,
                        const int* __restrict__ rowptr, int* __restrict__ cursor,
                        int* __restrict__ csr_src, int E, int n) {
    int team = blockIdx.x & (NTEAM - 1);
    int sub  = blockIdx.x >> 3;
    int nsub = gridDim.x >> 3;
    int nb   = (n + NTEAM - 1) / NTEAM;
    int lo = team * nb;
    int hi = min(n, lo + nb);
    for (int e = sub * blockDim.x + threadIdx.x; e < E; e += nsub * blockDim.x) {
        int d = dst[e];
        if (d >= lo && d < hi) {
            int p = rowptr[d] + atomicAdd(&cursor[d], 1);
            csr_src[p] = src[e];
        }
    }
}

__global__ void k_dinv(const int* __restrict__ cnt, float* __restrict__ dinv, int n) {
    int i = blockIdx.x * blockDim.x + threadIdx.x;
    if (i < n) dinv[i] = rsqrtf(1.0f + (float)cnt[i]);
}

// Per-block (1024 elems) sum of cnt -> bsum[b]
__global__ void k_scan_bsum(const int* __restrict__ cnt, int* __restrict__ bsum, int n) {
    __shared__ int lds[256];
    int base = blockIdx.x * 1024;
    int s = 0;
    for (int i = threadIdx.x; i < 1024; i += 256) {
        int g = base + i;
        if (g < n) s += cnt[g];
    }
    lds[threadIdx.x] = s;
    __syncthreads();
    for (int off = 128; off > 0; off >>= 1) {
        if (threadIdx.x < off) lds[threadIdx.x] += lds[threadIdx.x + off];
        __syncthreads();
    }
    if (threadIdx.x == 0) bsum[blockIdx.x] = lds[0];
}

// Exclusive scan of bsum (nb ~ 98, single thread is fine); also rowptr[n]=total.
__global__ void k_scan_off(int* __restrict__ bsum, int* __restrict__ rowptr, int nb, int n) {
    if (blockIdx.x == 0 && threadIdx.x == 0) {
        int run = 0;
        for (int i = 0; i < nb; i++) { int t = bsum[i]; bsum[i] = run; run += t; }
        rowptr[n] = run;
    }
}

// Final: exclusive scan within block + block offset -> rowptr[i]
__global__ void k_scan_final(const int* __restrict__ cnt, const int* __restrict__ bsum,
                             int* __restrict__ rowptr, int n) {
    __shared__ int lds[256];
    int base = blockIdx.x * 1024;
    int idx0 = base + threadIdx.x * 4;
    int v[4];
    #pragma unroll
    for (int i = 0; i < 4; i++) { int g = idx0 + i; v[i] = (g < n) ? cnt[g] : 0; }
    int t = v[0] + v[1] + v[2] + v[3];
    lds[threadIdx.x] = t;
    __syncthreads();
    for (int off = 1; off < 256; off <<= 1) {
        int val = lds[threadIdx.x];
        int add = (threadIdx.x >= off) ? lds[threadIdx.x - off] : 0;
        __syncthreads();
        lds[threadIdx.x] = val + add;
        __syncthreads();
    }
    int run = (threadIdx.x ? lds[threadIdx.x - 1] : 0) + bsum[blockIdx.x];
    #pragma unroll
    for (int i = 0; i < 4; i++) {
        int g = idx0 + i;
        if (g < n) rowptr[g] = run;
        run += v[i];
    }
}

// xw1 = x[n,128] @ W1[128,64]. Thread-per-row; acc[64] in VGPRs (all indices
// compile-time via full unroll); W1 addresses are lane-uniform -> scalar loads.
__global__ __launch_bounds__(256) void k_gemm1(const float* __restrict__ x,
                                               const float* __restrict__ W1,
                                               float* __restrict__ xw, int n) {
    int row = blockIdx.x * blockDim.x + threadIdx.x;
    if (row >= n) return;
    const float* xr = x + (size_t)row * 128;

    float acc[64];
    #pragma unroll
    for (int c = 0; c < 64; ++c) acc[c] = 0.f;

    for (int k4 = 0; k4 < 32; ++k4) {  // dynamic loop: small body, x read once
        float4 xv = *reinterpret_cast<const float4*>(xr + k4 * 4);
        const float* wp = W1 + (size_t)k4 * 4 * 64;  // rows k4*4 .. k4*4+3
        #pragma unroll
        for (int c = 0; c < 64; ++c) {
            acc[c] = fmaf(xv.x, wp[c], acc[c]);
            acc[c] = fmaf(xv.y, wp[64 + c], acc[c]);
            acc[c] = fmaf(xv.z, wp[128 + c], acc[c]);
            acc[c] = fmaf(xv.w, wp[192 + c], acc[c]);
        }
    }

    float* outp = xw + (size_t)row * 64;
    #pragma unroll
    for (int c = 0; c < 64; c += 4) {
        *reinterpret_cast<float4*>(outp + c) =
            make_float4(acc[c], acc[c + 1], acc[c + 2], acc[c + 3]);
    }
}

// Fused layer1 aggregate + tanh + GEMM2 (64->2 via wave reduction).
// One wave per dst node; lane = feature.
__global__ void k_agg1(const int* __restrict__ rowptr, const int* __restrict__ csr_src,
                       const float* __restrict__ dinv, const float* __restrict__ xw1,
                       const float* __restrict__ b1, const float* __restrict__ W2,
                       float* __restrict__ xw2, int n) {
    int lane = threadIdx.x & 63;
    float b1v = b1[lane];
    float w2a = W2[lane * 2 + 0];
    float w2b = W2[lane * 2 + 1];
    int wid = blockIdx.x * (blockDim.x >> 6) + (threadIdx.x >> 6);
    int wtot = gridDim.x * (blockDim.x >> 6);
    for (int d = wid; d < n; d += wtot) {
        int base = rowptr[d], end = rowptr[d + 1];
        float dd = dinv[d];
        float acc = xw1[(size_t)d * 64 + lane] * dd * dd;  // self loop
        int j = base;
        for (; j + 4 <= end; j += 4) {
            int s0 = csr_src[j + 0], s1 = csr_src[j + 1];
            int s2 = csr_src[j + 2], s3 = csr_src[j + 3];
            float n0 = dinv[s0] * dd, n1 = dinv[s1] * dd;
            float n2 = dinv[s2] * dd, n3 = dinv[s3] * dd;
            float v0 = xw1[(size_t)s0 * 64 + lane];
            float v1 = xw1[(size_t)s1 * 64 + lane];
            float v2 = xw1[(size_t)s2 * 64 + lane];
            float v3 = xw1[(size_t)s3 * 64 + lane];
            acc = fmaf(v0, n0, acc);
            acc = fmaf(v1, n1, acc);
            acc = fmaf(v2, n2, acc);
            acc = fmaf(v3, n3, acc);
        }
        for (; j < end; ++j) {
            int s = csr_src[j];
            acc = fmaf(xw1[(size_t)s * 64 + lane], dinv[s] * dd, acc);
        }
        float h = tanhf(acc + b1v);
        float p0 = h * w2a, p1 = h * w2b;
        #pragma unroll
        for (int m = 32; m >= 1; m >>= 1) {
            p0 += __shfl_xor(p0, m);
            p1 += __shfl_xor(p1, m);
        }
        if (lane == 0) *reinterpret_cast<float2*>(xw2 + (size_t)d * 2) = make_float2(p0, p1);
    }
}

// Fused layer2 aggregate + tanh + classifier. One wave per node:
// 32 edge-slots x 2 features in parallel, shfl tree reduce over slots.
__global__ void k_agg2(const int* __restrict__ rowptr, const int* __restrict__ csr_src,
                       const float* __restrict__ dinv, const float* __restrict__ xw2,
                       const float* __restrict__ b2, const float* __restrict__ Wc,
                       const float* __restrict__ bc,
                       float* __restrict__ out, float* __restrict__ hout, int n) {
    int lane = threadIdx.x & 63;
    int slot = lane >> 1;  // 0..31
    int f = lane & 1;      // feature 0/1
    float b2v = b2[f];
    int wid = blockIdx.x * (blockDim.x >> 6) + (threadIdx.x >> 6);
    int wtot = gridDim.x * (blockDim.x >> 6);
    for (int d = wid; d < n; d += wtot) {
        int base = rowptr[d], end = rowptr[d + 1];
        float dd = dinv[d];
        float acc = (slot == 0) ? xw2[(size_t)d * 2 + f] * dd * dd : 0.f;  // self loop once
        for (int j = base + slot; j < end; j += 32) {
            int s = csr_src[j];
            acc = fmaf(xw2[(size_t)s * 2 + f], dinv[s] * dd, acc);
        }
        #pragma unroll
        for (int m = 32; m >= 2; m >>= 1) acc += __shfl_xor(acc, m);
        float h = tanhf(acc + b2v);          // lane0: h(f=0), lane1: h(f=1), replicated
        float other = __shfl_xor(h, 1);
        if (lane == 0) {
            *reinterpret_cast<float2*>(hout + (size_t)d * 2) = make_float2(h, other);
            float4 o;
            o.x = fmaf(h, Wc[0], fmaf(other, Wc[4], bc[0]));
            o.y = fmaf(h, Wc[1], fmaf(other, Wc[5], bc[1]));
            o.z = fmaf(h, Wc[2], fmaf(other, Wc[6], bc[2]));
            o.w = fmaf(h, Wc[3], fmaf(other, Wc[7], bc[3]));
            *reinterpret_cast<float4*>(out + (size_t)d * 4) = o;
        }
    }
}

extern "C" void kernel_launch(void* const* d_in, const int* in_sizes, int n_in,
                              void* d_out, int out_size, void* d_ws, size_t ws_size,
                              hipStream_t stream) {
    const float* x  = (const float*)d_in[0];
    const int* ei   = (const int*)d_in[1];
    const float* W1 = (const float*)d_in[2];
    const float* b1 = (const float*)d_in[3];
    const float* W2 = (const float*)d_in[4];
    const float* b2 = (const float*)d_in[5];
    const float* Wc = (const float*)d_in[6];
    const float* bc = (const float*)d_in[7];

    const int N = in_sizes[0] / 128;
    const int E = in_sizes[1] / 2;
    const int* src = ei;
    const int* dst = ei + E;

    float* out  = (float*)d_out;        // [N,4]
    float* hout = out + (size_t)N * 4;  // [N,2]

    // Workspace layout (keep 16B alignment: big 16-divisible arrays first).
    char* ws = (char*)d_ws;
    int*   csr_src = (int*)ws;                           // E
    float* xw1     = (float*)(csr_src + E);              // 64N
    int*   cnt     = (int*)(xw1 + (size_t)N * 64);       // N (hist, then cursor)
    float* dinv    = (float*)(cnt + N);                  // N
    float* xw2     = dinv + N;                           // 2N
    int*   rowptr  = (int*)(xw2 + (size_t)N * 2);        // N+1
    int*   bsum    = rowptr + N + 1;                     // ~128

    const int NB = (N + 1023) / 1024;

    hipMemsetAsync(cnt, 0, (size_t)N * sizeof(int), stream);
    k_hist8<<<2048, 256, 0, stream>>>(dst, cnt, E, N);
    k_dinv<<<(N + 255) / 256, 256, 0, stream>>>(cnt, dinv, N);
    k_scan_bsum<<<NB, 256, 0, stream>>>(cnt, bsum, N);
    k_scan_off<<<1, 64, 0, stream>>>(bsum, rowptr, NB, N);
    k_scan_final<<<NB, 256, 0, stream>>>(cnt, bsum, rowptr, N);
    hipMemsetAsync(cnt, 0, (size_t)N * sizeof(int), stream);  // reuse as cursor
    k_fill8<<<2048, 256, 0, stream>>>(src, dst, rowptr, cnt, csr_src, E, N);

    k_gemm1<<<(N + 255) / 256, 256, 0, stream>>>(x, W1, xw1, N);
    k_agg1<<<2048, 256, 0, stream>>>(rowptr, csr_src, dinv, xw1, b1, W2, xw2, N);
    k_agg2<<<2048, 256, 0, stream>>>(rowptr, csr_src, dinv, xw2, b2, Wc, bc, out, hout, N);
}